// Round 17
// baseline (752.337 us; speedup 1.0000x reference)
//
#include <hip/hip_runtime.h>

#define SEQ 512
#define BATCH 64
#define NN 1024
#define SS 64

typedef float v4f __attribute__((ext_vector_type(4)));
typedef unsigned long long u64;

// lgkm-only barrier (no vmcnt drain) — fallback kernel only
#define RAW_BARRIER() asm volatile("s_waitcnt lgkmcnt(0)\n\ts_barrier" ::: "memory")

// ---- transpose W1 (1024x1024 f32): W1T[i*N+j] = W1[j*N+i] ----
__global__ void transpose1(const float* __restrict__ A, float* __restrict__ At) {
    __shared__ float tile[32][33];
    int bx = blockIdx.x * 32, by = blockIdx.y * 32;
    int tx = threadIdx.x, ty = threadIdx.y;   // block 32x8
#pragma unroll
    for (int r = 0; r < 32; r += 8)
        tile[ty + r][tx] = A[(by + ty + r) * NN + (bx + tx)];
    __syncthreads();
#pragma unroll
    for (int r = 0; r < 32; r += 8)
        At[(bx + ty + r) * NN + (by + tx)] = tile[tx][ty + r];
}

// ---- identity ids pattern for ALL (t,b) rows of ids1|ids2 (exact when no
// spikes; fallback overwrites flagged batches later in stream order) ----
__global__ __launch_bounds__(256) void ids_fill(float* __restrict__ out_ids) {
    const int idx = blockIdx.x * 256 + threadIdx.x;       // one v4f per thread
    const int p4  = (idx & 15) << 2;                      // position in 64-row
    const v4f val = {(float)p4, (float)(p4 + 1), (float)(p4 + 2), (float)(p4 + 3)};
    __builtin_nontemporal_store(val, (v4f*)(out_ids + (size_t)idx * 4));
}

// ---- phase 1: I1[tt,b,n] = sum_{s<num} W1T[ids[s], n] (R15-proven config:
// cached store so scan reads hit L2/L3) ----
__global__ __launch_bounds__(256) void gather_kernel(
    const float* __restrict__ W1T,
    const int* __restrict__ inp_ids, const int* __restrict__ inp_num,
    float* __restrict__ I1buf, int t0)
{
    const int bid = blockIdx.x;
    const int tt  = bid >> 6;
    const int b   = bid & 63;
    const int t   = t0 + tt;
    const int j4  = threadIdx.x << 2;
    const int num = inp_num[t * BATCH + b];
    const int* ids = inp_ids + ((size_t)t * BATCH + b) * SS;  // uniform -> s_load

    v4f a0 = {0,0,0,0}, a1 = a0, a2 = a0, a3 = a0;
    const int nch = num >> 2;
    const int rem = num & 3;
#pragma unroll
    for (int c = 0; c < 16; ++c) {
        if (c < nch) {                             // block-uniform
            const int r = c << 2;
            const v4f w0 = *(const v4f*)(W1T + ((size_t)ids[r+0] << 10) + j4);
            const v4f w1 = *(const v4f*)(W1T + ((size_t)ids[r+1] << 10) + j4);
            const v4f w2 = *(const v4f*)(W1T + ((size_t)ids[r+2] << 10) + j4);
            const v4f w3 = *(const v4f*)(W1T + ((size_t)ids[r+3] << 10) + j4);
#pragma unroll
            for (int k = 0; k < 4; ++k) {
                a0[k] = __fadd_rn(a0[k], w0[k]);
                a1[k] = __fadd_rn(a1[k], w1[k]);
                a2[k] = __fadd_rn(a2[k], w2[k]);
                a3[k] = __fadd_rn(a3[k], w3[k]);
            }
        }
    }
    if (rem > 0) {
        const int r4 = nch << 2;
        const v4f w0 = *(const v4f*)(W1T + ((size_t)ids[r4+0] << 10) + j4);
#pragma unroll
        for (int k = 0; k < 4; ++k) a0[k] = __fadd_rn(a0[k], w0[k]);
        if (rem > 1) {
            const v4f w1 = *(const v4f*)(W1T + ((size_t)ids[r4+1] << 10) + j4);
#pragma unroll
            for (int k = 0; k < 4; ++k) a1[k] = __fadd_rn(a1[k], w1[k]);
        }
        if (rem > 2) {
            const v4f w2 = *(const v4f*)(W1T + ((size_t)ids[r4+2] << 10) + j4);
#pragma unroll
            for (int k = 0; k < 4; ++k) a2[k] = __fadd_rn(a2[k], w2[k]);
        }
    }
    v4f o;
#pragma unroll
    for (int k = 0; k < 4; ++k)
        o[k] = __fadd_rn(__fadd_rn(a0[k], a1[k]), __fadd_rn(a2[k], a3[k]));
    *(v4f*)(I1buf + ((size_t)tt * BATCH + b) * NN + j4) = o;   // cached store
}

// ---- phase 2a: lane-local scan (R15-proven config: 4 neurons/thread,
// 256 blocks, cached I1 reads). ids written by ids_fill; counts published
// via exact float atomicAdd (integer-valued, < 2^24) into zeroed cnt outputs.
__global__ __launch_bounds__(64) void scan_kernel(
    const float* __restrict__ I1buf,
    const float* __restrict__ decay1, const float* __restrict__ decay2,
    const float* __restrict__ th1, const float* __restrict__ th2,
    const float* __restrict__ init1, const float* __restrict__ init2,
    const float* __restrict__ state_in, float* __restrict__ state_out,
    unsigned* __restrict__ flags, float* __restrict__ out, int t0, int nst)
{
    const int bid = blockIdx.x;
    const int b   = bid >> 2;
    const int q   = bid & 3;
    const int tid = threadIdx.x;            // 0..63 (one wave)
    const int n0  = (q << 8) + (tid << 2);  // neurons n0..n0+3

    float v1[4], v2[4], d1v[4], d2v[4], o1v[4];
    float t1v[4], t2v[4], t1bv[4], t2bv[4];
    const float* v1src = t0 ? (state_in + 0 * BATCH * NN) : init1;
    const float* v2src = t0 ? (state_in + 1 * BATCH * NN) : init2;
#pragma unroll
    for (int k = 0; k < 4; ++k) {
        const int n = n0 + k;
        v1[k] = v1src[b * NN + n];  v2[k] = v2src[b * NN + n];
        d1v[k] = decay1[n];  d2v[k] = decay2[n];
        t1v[k] = th1[n];     t2v[k] = th2[n];
        t1bv[k] = __fmul_rn(0.9f, t1v[k]);
        t2bv[k] = __fmul_rn(0.9f, t2v[k]);
        o1v[k] = __fadd_rn(1.0f, -d1v[k]);
    }

    float* out_cnt1 = out + (size_t)2 * SEQ * BATCH * SS;
    float* out_cnt2 = out_cnt1 + (size_t)SEQ * BATCH * 2;
    float* out_st1  = out_cnt2 + (size_t)SEQ * BATCH * 2;
    float* out_st2  = out_st1 + (size_t)SEQ * BATCH * NN;

    u64 anyspike = 0;

    // depth-8 I1 prefetch ring (static indices; tail-clamped loads harmless)
    v4f f[8];
#pragma unroll
    for (int j = 0; j < 8; ++j) {
        const int tt = (j < nst) ? j : (nst - 1);
        f[j] = *(const v4f*)(I1buf + ((size_t)tt * BATCH + b) * NN + n0);
    }

    for (int g = 0; g < nst; g += 8) {
#pragma unroll
        for (int j = 0; j < 8; ++j) {
            const int tt = g + j;
            if (tt < nst) {                        // uniform guard
                const v4f cur = f[j];
                const int tp = (tt + 8 < nst) ? (tt + 8) : (nst - 1);
                f[j] = *(const v4f*)(I1buf + ((size_t)tp * BATCH + b) * NN + n0);

                u64 B1[4], Bn1[4], B2[4], Bn2[4];
#pragma unroll
                for (int k = 0; k < 4; ++k) {
                    v1[k] = __fadd_rn(__fmul_rn(d1v[k], v1[k]),
                                      __fmul_rn(o1v[k], cur[k]));
                    B1[k]  = __ballot(v1[k] > t1v[k]);
                    Bn1[k] = __ballot(v1[k] > t1bv[k]);
                    if ((B1[k] >> tid) & 1ull) v1[k] = 0.0f;     // exact reset
                    v2[k] = __fmul_rn(d2v[k], v2[k]);            // I2=0 spec
                    B2[k]  = __ballot(v2[k] > t2v[k]);
                    Bn2[k] = __ballot(v2[k] > t2bv[k]);
                    if ((B2[k] >> tid) & 1ull) v2[k] = 0.0f;     // exact reset
                }
                anyspike |= B1[0] | B1[1] | B1[2] | B1[3]
                          | B2[0] | B2[1] | B2[2] | B2[3];

                const size_t row = (size_t)(t0 + tt) * BATCH + b;
                if (tid == 0) {
                    const int c1  = (int)(__popcll(B1[0]) + __popcll(B1[1])
                                        + __popcll(B1[2]) + __popcll(B1[3]));
                    const int cn1 = (int)(__popcll(Bn1[0]) + __popcll(Bn1[1])
                                        + __popcll(Bn1[2]) + __popcll(Bn1[3]));
                    const int c2  = (int)(__popcll(B2[0]) + __popcll(B2[1])
                                        + __popcll(B2[2]) + __popcll(B2[3]));
                    const int cn2 = (int)(__popcll(Bn2[0]) + __popcll(Bn2[1])
                                        + __popcll(Bn2[2]) + __popcll(Bn2[3]));
                    // exact: integer-valued float adds, cnt zeroed up front
                    atomicAdd(&out_cnt1[row * 2 + 0], (float)c1);
                    atomicAdd(&out_cnt1[row * 2 + 1], (float)cn1);
                    atomicAdd(&out_cnt2[row * 2 + 0], (float)c2);
                    atomicAdd(&out_cnt2[row * 2 + 1], (float)cn2);
                }

                const v4f s1 = {v1[0], v1[1], v1[2], v1[3]};
                const v4f s2 = {v2[0], v2[1], v2[2], v2[3]};
                __builtin_nontemporal_store(s1, (v4f*)(out_st1 + row * NN + n0));
                __builtin_nontemporal_store(s2, (v4f*)(out_st2 + row * NN + n0));
            }
        }
    }

    if (anyspike && tid == 0) flags[b] = 1u;       // batch needs exact fallback

#pragma unroll
    for (int k = 0; k < 4; ++k) {
        state_out[0 * BATCH * NN + b * NN + n0 + k] = v1[k];
        state_out[1 * BATCH * NN + b * NN + n0 + k] = v2[k];
    }
}

// ---- phase 2c: exact fallback (R13 lif body), only for flagged batches ----
__global__ __launch_bounds__(256, 1) void fallback_kernel(
    const float* __restrict__ I1buf, const float* __restrict__ W2,
    const float* __restrict__ decay1, const float* __restrict__ decay2,
    const float* __restrict__ th1, const float* __restrict__ th2,
    const float* __restrict__ init1, const float* __restrict__ init2,
    const float* __restrict__ state_in, float* __restrict__ state_out,
    const unsigned* __restrict__ flags, float* __restrict__ out,
    int t0, int nsteps)
{
    const int b = blockIdx.x;
    if (flags[b] == 0u) return;                    // common case: null work

    const int i    = threadIdx.x;
    const int lane = i & 63;
    const int w    = i >> 6;
    const int n0   = i << 2;

    __shared__ u64 lds_w[2][4];
    __shared__ u64 lds_wc[2][4];
    __shared__ int lds_slots[NN];

    float v1[4], v2[4], d1v[4], d2v[4], o1v[4], o2v[4];
    float t1v[4], t2v[4], t1bv[4], t2bv[4];
    const float* v1src = t0 ? (state_in + 0 * BATCH * NN) : init1;
    const float* v2src = t0 ? (state_in + 1 * BATCH * NN) : init2;
#pragma unroll
    for (int k = 0; k < 4; ++k) {
        const int n = n0 + k;
        v1[k] = v1src[b * NN + n];  v2[k] = v2src[b * NN + n];
        d1v[k] = decay1[n];  d2v[k] = decay2[n];
        t1v[k] = th1[n];     t2v[k] = th2[n];
        t1bv[k] = __fmul_rn(0.9f, t1v[k]);
        t2bv[k] = __fmul_rn(0.9f, t2v[k]);
        o1v[k] = __fadd_rn(1.0f, -d1v[k]);
        o2v[k] = __fadd_rn(1.0f, -d2v[k]);
    }

    float* out_ids1 = out;
    float* out_ids2 = out + (size_t)SEQ * BATCH * SS;
    float* out_cnt1 = out + (size_t)2 * SEQ * BATCH * SS;
    float* out_cnt2 = out_cnt1 + (size_t)SEQ * BATCH * 2;
    float* out_st1  = out_cnt2 + (size_t)SEQ * BATCH * 2;
    float* out_st2  = out_st1  + (size_t)SEQ * BATCH * NN;

    const u64 lmask_lt = (1ull << lane) - 1ull;

    u64 B1p[4], B2p[4];
    float v2pp[4];

    auto CONSUME = [&](int s, int ppar) {
        const u64* wp = lds_w[ppar];
        const u64 x0 = wp[0], x1 = wp[1], x2 = wp[2], x3 = wp[3];
        const u64 tot = x0 + x1 + x2 + x3;
        const u64 off = (w > 0 ? x0 : 0) + (w > 1 ? x1 : 0) + (w > 2 ? x2 : 0);
        const int totalA  = (int)(tot & 0xFFFF);
        const int total2A = (int)((tot >> 16) & 0xFFFF);
        const int woff1   = (int)(off & 0xFFFF);

        const int T1 = (int)(__popcll(B1p[0] & lmask_lt) + __popcll(B1p[1] & lmask_lt)
                           + __popcll(B1p[2] & lmask_lt) + __popcll(B1p[3] & lmask_lt));
        const size_t row = (size_t)s * BATCH + b;

        int run = 0;
        int lt1s[4]; bool bk1[4];
#pragma unroll
        for (int k = 0; k < 4; ++k) {
            bk1[k] = (B1p[k] >> lane) & 1ull;
            lt1s[k] = woff1 + T1 + run;
            run += bk1[k];
            const int slot = bk1[k] ? lt1s[k] : (totalA + (n0 + k) - lt1s[k]);
            if (slot < SS)
                __builtin_nontemporal_store((float)(n0 + k),
                                            &out_ids1[row * SS + slot]);
        }
        {
            const v4f sv = {v1[0], v1[1], v1[2], v1[3]};
            __builtin_nontemporal_store(sv, (v4f*)(out_st1 + row * NN + n0));
        }
        if (i == 0) {
            __builtin_nontemporal_store((float)totalA,  &out_cnt1[row * 2 + 0]);
            __builtin_nontemporal_store((float)total2A, &out_cnt1[row * 2 + 1]);
        }

        int totalB, total2B, woff2;
        u64 B2u[4]; float v2u[4];
        if (totalA > 0) {
#pragma unroll
            for (int k = 0; k < 4; ++k)
                if (bk1[k]) lds_slots[lt1s[k]] = n0 + k;
            RAW_BARRIER();
            float I2[4] = {0.0f, 0.0f, 0.0f, 0.0f};
            for (int kk = 0; kk < totalA; ++kk) {
                const int sid = lds_slots[kk];
#pragma unroll
                for (int k = 0; k < 4; ++k)
                    I2[k] = __fadd_rn(I2[k], W2[(size_t)(n0 + k) * NN + sid]);
            }
            u64 Bn2c[4];
#pragma unroll
            for (int k = 0; k < 4; ++k) {
                v2u[k] = __fadd_rn(v2pp[k], __fmul_rn(o2v[k], I2[k]));
                B2u[k] = __ballot(v2u[k] > t2v[k]);
                Bn2c[k] = __ballot(v2u[k] > t2bv[k]);
            }
            const u64 c2c  = __popcll(B2u[0]) + __popcll(B2u[1])
                           + __popcll(B2u[2]) + __popcll(B2u[3]);
            const u64 cn2c = __popcll(Bn2c[0]) + __popcll(Bn2c[1])
                           + __popcll(Bn2c[2]) + __popcll(Bn2c[3]);
            if (lane == 0) lds_wc[ppar][w] = c2c | (cn2c << 16);
            RAW_BARRIER();
            const u64* cp = lds_wc[ppar];
            const u64 ct = cp[0] + cp[1] + cp[2] + cp[3];
            const u64 co = (w > 0 ? cp[0] : 0) + (w > 1 ? cp[1] : 0)
                         + (w > 2 ? cp[2] : 0);
            totalB  = (int)(ct & 0xFFFF);
            total2B = (int)((ct >> 16) & 0xFFFF);
            woff2   = (int)(co & 0xFFFF);
        } else {
#pragma unroll
            for (int k = 0; k < 4; ++k) { B2u[k] = B2p[k]; v2u[k] = v2pp[k]; }
            totalB  = (int)((tot >> 32) & 0xFFFF);
            total2B = (int)(tot >> 48);
            woff2   = (int)((off >> 32) & 0xFFFF);
        }

        const int T2 = (int)(__popcll(B2u[0] & lmask_lt) + __popcll(B2u[1] & lmask_lt)
                           + __popcll(B2u[2] & lmask_lt) + __popcll(B2u[3] & lmask_lt));
        int run2 = 0;
        v4f sv2;
#pragma unroll
        for (int k = 0; k < 4; ++k) {
            const bool bk = (B2u[k] >> lane) & 1ull;
            const int lt = woff2 + T2 + run2;
            run2 += bk;
            const int slot = bk ? lt : (totalB + (n0 + k) - lt);
            if (slot < SS)
                __builtin_nontemporal_store((float)(n0 + k),
                                            &out_ids2[row * SS + slot]);
            sv2[k] = bk ? 0.0f : v2u[k];
            v2[k] = sv2[k];
        }
        __builtin_nontemporal_store(sv2, (v4f*)(out_st2 + row * NN + n0));
        if (i == 0) {
            __builtin_nontemporal_store((float)totalB,  &out_cnt2[row * 2 + 0]);
            __builtin_nontemporal_store((float)total2B, &out_cnt2[row * 2 + 1]);
        }
    };

    v4f f0 = *(const v4f*)(I1buf + ((size_t)0 * BATCH + b) * NN + n0);
    v4f f1 = (nsteps > 1)
        ? *(const v4f*)(I1buf + ((size_t)1 * BATCH + b) * NN + n0) : f0;

    for (int tt = 0; tt < nsteps; ++tt) {
        const int par = tt & 1;
        v4f f2 = f0;
        if (tt + 2 < nsteps)
            f2 = *(const v4f*)(I1buf + ((size_t)(tt + 2) * BATCH + b) * NN + n0);

        if (tt > 0) CONSUME(t0 + tt - 1, par ^ 1);

        const v4f f = f0; f0 = f1; f1 = f2;
        u64 Bn1[4], Bn2[4];
#pragma unroll
        for (int k = 0; k < 4; ++k) {
            v1[k] = __fadd_rn(__fmul_rn(d1v[k], v1[k]), __fmul_rn(o1v[k], f[k]));
            B1p[k] = __ballot(v1[k] > t1v[k]);
            Bn1[k] = __ballot(v1[k] > t1bv[k]);
            if ((B1p[k] >> lane) & 1ull) v1[k] = 0.0f;
            v2pp[k] = __fmul_rn(d2v[k], v2[k]);
            B2p[k] = __ballot(v2pp[k] > t2v[k]);
            Bn2[k] = __ballot(v2pp[k] > t2bv[k]);
        }
        const u64 c1  = __popcll(B1p[0]) + __popcll(B1p[1])
                      + __popcll(B1p[2]) + __popcll(B1p[3]);
        const u64 cn1 = __popcll(Bn1[0]) + __popcll(Bn1[1])
                      + __popcll(Bn1[2]) + __popcll(Bn1[3]);
        const u64 c2  = __popcll(B2p[0]) + __popcll(B2p[1])
                      + __popcll(B2p[2]) + __popcll(B2p[3]);
        const u64 cn2 = __popcll(Bn2[0]) + __popcll(Bn2[1])
                      + __popcll(Bn2[2]) + __popcll(Bn2[3]);
        if (lane == 0)
            lds_w[par][w] = c1 | (cn1 << 16) | (c2 << 32) | (cn2 << 48);

        RAW_BARRIER();
    }

    CONSUME(t0 + nsteps - 1, (nsteps - 1) & 1);

#pragma unroll
    for (int k = 0; k < 4; ++k) {
        state_out[0 * BATCH * NN + b * NN + n0 + k] = v1[k];
        state_out[1 * BATCH * NN + b * NN + n0 + k] = v2[k];
    }
}

extern "C" void kernel_launch(void* const* d_in, const int* in_sizes, int n_in,
                              void* d_out, int out_size, void* d_ws, size_t ws_size,
                              hipStream_t stream) {
    const float* W1     = (const float*)d_in[0];
    const float* W2     = (const float*)d_in[1];
    const float* decay1 = (const float*)d_in[2];
    const float* decay2 = (const float*)d_in[3];
    const float* th1    = (const float*)d_in[4];
    const float* th2    = (const float*)d_in[5];
    const float* init1  = (const float*)d_in[6];
    const float* init2  = (const float*)d_in[7];
    const int* inp_ids  = (const int*)d_in[8];
    const int* inp_num  = (const int*)d_in[9];
    float* out = (float*)d_out;

    char* p = (char*)d_ws;
    float* W1T    = (float*)p;                         p += (size_t)NN * NN * 4;
    float* stateA = (float*)p;                         p += (size_t)2 * BATCH * NN * 4;
    float* stateB = (float*)p;                         p += (size_t)2 * BATCH * NN * 4;
    unsigned* flags = (unsigned*)p;                    p += 256;
    float* I1buf  = (float*)p;
    const size_t used  = (size_t)(p - (char*)d_ws);
    const size_t avail = ws_size > used ? ws_size - used : 0;
    int tc = (int)(avail / ((size_t)BATCH * NN * 4));
    if (tc > SEQ) tc = SEQ;
    if (tc < 1) tc = 1;

    float* out_cnt = out + (size_t)2 * SEQ * BATCH * SS;

    dim3 tb(32, 8, 1), tg(NN / 32, NN / 32, 1);
    transpose1<<<tg, tb, 0, stream>>>(W1, W1T);
    // identity ids for all (t,b) of both layers
    ids_fill<<<(2 * SEQ * BATCH * SS / 4) / 256, 256, 0, stream>>>(out);
    // zero both cnt regions (scan atomically accumulates into them)
    hipMemsetAsync(out_cnt, 0, (size_t)2 * SEQ * BATCH * 2 * 4, stream);

    float* sin  = stateA;
    float* sout = stateB;
    for (int t0 = 0; t0 < SEQ; t0 += tc) {
        const int nst = (SEQ - t0 < tc) ? (SEQ - t0) : tc;
        hipMemsetAsync(flags, 0, BATCH * sizeof(unsigned), stream);
        gather_kernel<<<nst * BATCH, 256, 0, stream>>>(W1T, inp_ids, inp_num,
                                                       I1buf, t0);
        scan_kernel<<<4 * BATCH, 64, 0, stream>>>(I1buf, decay1, decay2, th1, th2,
                                                  init1, init2, sin, sout,
                                                  flags, out, t0, nst);
        fallback_kernel<<<BATCH, 256, 0, stream>>>(I1buf, W2, decay1, decay2,
                                                   th1, th2, init1, init2,
                                                   sin, sout, flags, out, t0, nst);
        float* tmp = sin; sin = sout; sout = tmp;
    }
}

// Round 18
// 597.316 us; speedup vs baseline: 1.2595x; 1.2595x over previous
//
#include <hip/hip_runtime.h>

#define SEQ 512
#define BATCH 64
#define NN 1024
#define SS 64

typedef float v4f __attribute__((ext_vector_type(4)));
typedef unsigned long long u64;

// lgkm-only barrier (no vmcnt drain) — fallback path only
#define RAW_BARRIER() asm volatile("s_waitcnt lgkmcnt(0)\n\ts_barrier" ::: "memory")

// ---- transpose W1 (1024x1024 f32): W1T[i*N+j] = W1[j*N+i] ----
__global__ void transpose1(const float* __restrict__ A, float* __restrict__ At) {
    __shared__ float tile[32][33];
    int bx = blockIdx.x * 32, by = blockIdx.y * 32;
    int tx = threadIdx.x, ty = threadIdx.y;   // block 32x8
#pragma unroll
    for (int r = 0; r < 32; r += 8)
        tile[ty + r][tx] = A[(by + ty + r) * NN + (bx + tx)];
    __syncthreads();
#pragma unroll
    for (int r = 0; r < 32; r += 8)
        At[(bx + ty + r) * NN + (by + tx)] = tile[tx][ty + r];
}

// ---- identity ids pattern for ALL (t,b) rows of ids1|ids2 (exact when no
// spikes; fallback overwrites flagged batches later in stream order) ----
__global__ __launch_bounds__(256) void ids_fill(float* __restrict__ out_ids) {
    const int idx = blockIdx.x * 256 + threadIdx.x;       // one v4f per thread
    const int p4  = (idx & 15) << 2;                      // position in 64-row
    const v4f val = {(float)p4, (float)(p4 + 1), (float)(p4 + 2), (float)(p4 + 3)};
    __builtin_nontemporal_store(val, (v4f*)(out_ids + (size_t)idx * 4));
}

// ---- phase 1: I1[tt,b,n] = sum_{s<num} W1T[ids[s], n] (R15-proven config:
// cached store so scan reads hit L2/L3) ----
__global__ __launch_bounds__(256) void gather_kernel(
    const float* __restrict__ W1T,
    const int* __restrict__ inp_ids, const int* __restrict__ inp_num,
    float* __restrict__ I1buf, int t0)
{
    const int bid = blockIdx.x;
    const int tt  = bid >> 6;
    const int b   = bid & 63;
    const int t   = t0 + tt;
    const int j4  = threadIdx.x << 2;
    const int num = inp_num[t * BATCH + b];
    const int* ids = inp_ids + ((size_t)t * BATCH + b) * SS;  // uniform -> s_load

    v4f a0 = {0,0,0,0}, a1 = a0, a2 = a0, a3 = a0;
    const int nch = num >> 2;
    const int rem = num & 3;
#pragma unroll
    for (int c = 0; c < 16; ++c) {
        if (c < nch) {                             // block-uniform
            const int r = c << 2;
            const v4f w0 = *(const v4f*)(W1T + ((size_t)ids[r+0] << 10) + j4);
            const v4f w1 = *(const v4f*)(W1T + ((size_t)ids[r+1] << 10) + j4);
            const v4f w2 = *(const v4f*)(W1T + ((size_t)ids[r+2] << 10) + j4);
            const v4f w3 = *(const v4f*)(W1T + ((size_t)ids[r+3] << 10) + j4);
#pragma unroll
            for (int k = 0; k < 4; ++k) {
                a0[k] = __fadd_rn(a0[k], w0[k]);
                a1[k] = __fadd_rn(a1[k], w1[k]);
                a2[k] = __fadd_rn(a2[k], w2[k]);
                a3[k] = __fadd_rn(a3[k], w3[k]);
            }
        }
    }
    if (rem > 0) {
        const int r4 = nch << 2;
        const v4f w0 = *(const v4f*)(W1T + ((size_t)ids[r4+0] << 10) + j4);
#pragma unroll
        for (int k = 0; k < 4; ++k) a0[k] = __fadd_rn(a0[k], w0[k]);
        if (rem > 1) {
            const v4f w1 = *(const v4f*)(W1T + ((size_t)ids[r4+1] << 10) + j4);
#pragma unroll
            for (int k = 0; k < 4; ++k) a1[k] = __fadd_rn(a1[k], w1[k]);
        }
        if (rem > 2) {
            const v4f w2 = *(const v4f*)(W1T + ((size_t)ids[r4+2] << 10) + j4);
#pragma unroll
            for (int k = 0; k < 4; ++k) a2[k] = __fadd_rn(a2[k], w2[k]);
        }
    }
    v4f o;
#pragma unroll
    for (int k = 0; k < 4; ++k)
        o[k] = __fadd_rn(__fadd_rn(a0[k], a1[k]), __fadd_rn(a2[k], a3[k]));
    *(v4f*)(I1buf + ((size_t)tt * BATCH + b) * NN + j4) = o;   // cached store
}

// ---- phase 2a: lane-local scan — EXACT R15 config (4 neurons/thread,
// 256 blocks, cached I1, pc partial stores). Only delta vs R15: ids writes
// moved to ids_fill (removes 2 NT stores/step from the q0 straggler blocks).
__global__ __launch_bounds__(64) void scan_kernel(
    const float* __restrict__ I1buf,
    const float* __restrict__ decay1, const float* __restrict__ decay2,
    const float* __restrict__ th1, const float* __restrict__ th2,
    const float* __restrict__ init1, const float* __restrict__ init2,
    const float* __restrict__ state_in, float* __restrict__ state_out,
    u64* __restrict__ pc, unsigned* __restrict__ flags,
    float* __restrict__ out, int t0, int nst)
{
    const int bid = blockIdx.x;
    const int b   = bid >> 2;
    const int q   = bid & 3;
    const int tid = threadIdx.x;            // 0..63 (one wave)
    const int n0  = (q << 8) + (tid << 2);  // neurons n0..n0+3

    float v1[4], v2[4], d1v[4], d2v[4], o1v[4];
    float t1v[4], t2v[4], t1bv[4], t2bv[4];
    const float* v1src = t0 ? (state_in + 0 * BATCH * NN) : init1;
    const float* v2src = t0 ? (state_in + 1 * BATCH * NN) : init2;
#pragma unroll
    for (int k = 0; k < 4; ++k) {
        const int n = n0 + k;
        v1[k] = v1src[b * NN + n];  v2[k] = v2src[b * NN + n];
        d1v[k] = decay1[n];  d2v[k] = decay2[n];
        t1v[k] = th1[n];     t2v[k] = th2[n];
        t1bv[k] = __fmul_rn(0.9f, t1v[k]);
        t2bv[k] = __fmul_rn(0.9f, t2v[k]);
        o1v[k] = __fadd_rn(1.0f, -d1v[k]);
    }

    float* out_st1 = out + (size_t)2 * SEQ * BATCH * SS + (size_t)2 * SEQ * BATCH * 2;
    float* out_st2 = out_st1 + (size_t)SEQ * BATCH * NN;

    u64 anyspike = 0;

    // depth-8 I1 prefetch ring (static indices; tail-clamped loads harmless)
    v4f f[8];
#pragma unroll
    for (int j = 0; j < 8; ++j) {
        const int tt = (j < nst) ? j : (nst - 1);
        f[j] = *(const v4f*)(I1buf + ((size_t)tt * BATCH + b) * NN + n0);
    }

    for (int g = 0; g < nst; g += 8) {
#pragma unroll
        for (int j = 0; j < 8; ++j) {
            const int tt = g + j;
            if (tt < nst) {                        // uniform guard
                const v4f cur = f[j];
                const int tp = (tt + 8 < nst) ? (tt + 8) : (nst - 1);
                f[j] = *(const v4f*)(I1buf + ((size_t)tp * BATCH + b) * NN + n0);

                u64 B1[4], Bn1[4], B2[4], Bn2[4];
#pragma unroll
                for (int k = 0; k < 4; ++k) {
                    v1[k] = __fadd_rn(__fmul_rn(d1v[k], v1[k]),
                                      __fmul_rn(o1v[k], cur[k]));
                    B1[k]  = __ballot(v1[k] > t1v[k]);
                    Bn1[k] = __ballot(v1[k] > t1bv[k]);
                    if ((B1[k] >> tid) & 1ull) v1[k] = 0.0f;     // exact reset
                    v2[k] = __fmul_rn(d2v[k], v2[k]);            // I2=0 spec
                    B2[k]  = __ballot(v2[k] > t2v[k]);
                    Bn2[k] = __ballot(v2[k] > t2bv[k]);
                    if ((B2[k] >> tid) & 1ull) v2[k] = 0.0f;     // exact reset
                }
                anyspike |= B1[0] | B1[1] | B1[2] | B1[3]
                          | B2[0] | B2[1] | B2[2] | B2[3];

                const u64 c1  = __popcll(B1[0]) + __popcll(B1[1])
                              + __popcll(B1[2]) + __popcll(B1[3]);
                const u64 cn1 = __popcll(Bn1[0]) + __popcll(Bn1[1])
                              + __popcll(Bn1[2]) + __popcll(Bn1[3]);
                const u64 c2  = __popcll(B2[0]) + __popcll(B2[1])
                              + __popcll(B2[2]) + __popcll(B2[3]);
                const u64 cn2 = __popcll(Bn2[0]) + __popcll(Bn2[1])
                              + __popcll(Bn2[2]) + __popcll(Bn2[3]);
                if (tid == 0)
                    pc[((size_t)tt * BATCH + b) * 4 + q] =
                        c1 | (cn1 << 16) | (c2 << 32) | (cn2 << 48);

                const size_t row = (size_t)(t0 + tt) * BATCH + b;
                const v4f s1 = {v1[0], v1[1], v1[2], v1[3]};
                const v4f s2 = {v2[0], v2[1], v2[2], v2[3]};
                __builtin_nontemporal_store(s1, (v4f*)(out_st1 + row * NN + n0));
                __builtin_nontemporal_store(s2, (v4f*)(out_st2 + row * NN + n0));
            }
        }
    }

    if (anyspike && tid == 0) flags[b] = 1u;       // batch needs exact fallback

#pragma unroll
    for (int k = 0; k < 4; ++k) {
        state_out[0 * BATCH * NN + b * NN + n0 + k] = v1[k];
        state_out[1 * BATCH * NN + b * NN + n0 + k] = v2[k];
    }
}

// ---- phase 2b+2c merged: blocks [0,RB) reduce pc -> cnt outputs;
// blocks [RB,RB+64) run the exact fallback for flagged batches ----
__global__ __launch_bounds__(256, 1) void finish_kernel(
    const u64* __restrict__ pc,
    const float* __restrict__ I1buf, const float* __restrict__ W2,
    const float* __restrict__ decay1, const float* __restrict__ decay2,
    const float* __restrict__ th1, const float* __restrict__ th2,
    const float* __restrict__ init1, const float* __restrict__ init2,
    const float* __restrict__ state_in, float* __restrict__ state_out,
    const unsigned* __restrict__ flags, float* __restrict__ out,
    int t0, int nsteps, int RB)
{
    float* out_cnt1 = out + (size_t)2 * SEQ * BATCH * SS;
    float* out_cnt2 = out_cnt1 + (size_t)SEQ * BATCH * 2;

    if (blockIdx.x < RB) {
        // ---------------- reduce role ----------------
        const int idx = blockIdx.x * 256 + threadIdx.x;
        if (idx >= nsteps * BATCH) return;
        const int tt = idx >> 6;
        const int b  = idx & 63;
        const u64 s = pc[(size_t)idx * 4 + 0] + pc[(size_t)idx * 4 + 1]
                    + pc[(size_t)idx * 4 + 2] + pc[(size_t)idx * 4 + 3];
        const size_t row = (size_t)(t0 + tt) * BATCH + b;
        out_cnt1[row * 2 + 0] = (float)(s & 0xFFFF);
        out_cnt1[row * 2 + 1] = (float)((s >> 16) & 0xFFFF);
        out_cnt2[row * 2 + 0] = (float)((s >> 32) & 0xFFFF);
        out_cnt2[row * 2 + 1] = (float)(s >> 48);
        return;
    }

    // ---------------- fallback role (exact R13 lif body) ----------------
    const int b = blockIdx.x - RB;
    if (flags[b] == 0u) return;                    // common case: null work

    const int i    = threadIdx.x;
    const int lane = i & 63;
    const int w    = i >> 6;
    const int n0   = i << 2;

    __shared__ u64 lds_w[2][4];
    __shared__ u64 lds_wc[2][4];
    __shared__ int lds_slots[NN];

    float v1[4], v2[4], d1v[4], d2v[4], o1v[4], o2v[4];
    float t1v[4], t2v[4], t1bv[4], t2bv[4];
    const float* v1src = t0 ? (state_in + 0 * BATCH * NN) : init1;
    const float* v2src = t0 ? (state_in + 1 * BATCH * NN) : init2;
#pragma unroll
    for (int k = 0; k < 4; ++k) {
        const int n = n0 + k;
        v1[k] = v1src[b * NN + n];  v2[k] = v2src[b * NN + n];
        d1v[k] = decay1[n];  d2v[k] = decay2[n];
        t1v[k] = th1[n];     t2v[k] = th2[n];
        t1bv[k] = __fmul_rn(0.9f, t1v[k]);
        t2bv[k] = __fmul_rn(0.9f, t2v[k]);
        o1v[k] = __fadd_rn(1.0f, -d1v[k]);
        o2v[k] = __fadd_rn(1.0f, -d2v[k]);
    }

    float* out_ids1 = out;
    float* out_ids2 = out + (size_t)SEQ * BATCH * SS;
    float* out_st1  = out_cnt2 + (size_t)SEQ * BATCH * 2;
    float* out_st2  = out_st1  + (size_t)SEQ * BATCH * NN;

    const u64 lmask_lt = (1ull << lane) - 1ull;

    u64 B1p[4], B2p[4];
    float v2pp[4];

    auto CONSUME = [&](int s, int ppar) {
        const u64* wp = lds_w[ppar];
        const u64 x0 = wp[0], x1 = wp[1], x2 = wp[2], x3 = wp[3];
        const u64 tot = x0 + x1 + x2 + x3;
        const u64 off = (w > 0 ? x0 : 0) + (w > 1 ? x1 : 0) + (w > 2 ? x2 : 0);
        const int totalA  = (int)(tot & 0xFFFF);
        const int total2A = (int)((tot >> 16) & 0xFFFF);
        const int woff1   = (int)(off & 0xFFFF);

        const int T1 = (int)(__popcll(B1p[0] & lmask_lt) + __popcll(B1p[1] & lmask_lt)
                           + __popcll(B1p[2] & lmask_lt) + __popcll(B1p[3] & lmask_lt));
        const size_t row = (size_t)s * BATCH + b;

        int run = 0;
        int lt1s[4]; bool bk1[4];
#pragma unroll
        for (int k = 0; k < 4; ++k) {
            bk1[k] = (B1p[k] >> lane) & 1ull;
            lt1s[k] = woff1 + T1 + run;
            run += bk1[k];
            const int slot = bk1[k] ? lt1s[k] : (totalA + (n0 + k) - lt1s[k]);
            if (slot < SS)
                __builtin_nontemporal_store((float)(n0 + k),
                                            &out_ids1[row * SS + slot]);
        }
        {
            const v4f sv = {v1[0], v1[1], v1[2], v1[3]};
            __builtin_nontemporal_store(sv, (v4f*)(out_st1 + row * NN + n0));
        }
        if (i == 0) {
            __builtin_nontemporal_store((float)totalA,  &out_cnt1[row * 2 + 0]);
            __builtin_nontemporal_store((float)total2A, &out_cnt1[row * 2 + 1]);
        }

        int totalB, total2B, woff2;
        u64 B2u[4]; float v2u[4];
        if (totalA > 0) {
#pragma unroll
            for (int k = 0; k < 4; ++k)
                if (bk1[k]) lds_slots[lt1s[k]] = n0 + k;
            RAW_BARRIER();
            float I2[4] = {0.0f, 0.0f, 0.0f, 0.0f};
            for (int kk = 0; kk < totalA; ++kk) {
                const int sid = lds_slots[kk];
#pragma unroll
                for (int k = 0; k < 4; ++k)
                    I2[k] = __fadd_rn(I2[k], W2[(size_t)(n0 + k) * NN + sid]);
            }
            u64 Bn2c[4];
#pragma unroll
            for (int k = 0; k < 4; ++k) {
                v2u[k] = __fadd_rn(v2pp[k], __fmul_rn(o2v[k], I2[k]));
                B2u[k] = __ballot(v2u[k] > t2v[k]);
                Bn2c[k] = __ballot(v2u[k] > t2bv[k]);
            }
            const u64 c2c  = __popcll(B2u[0]) + __popcll(B2u[1])
                           + __popcll(B2u[2]) + __popcll(B2u[3]);
            const u64 cn2c = __popcll(Bn2c[0]) + __popcll(Bn2c[1])
                           + __popcll(Bn2c[2]) + __popcll(Bn2c[3]);
            if (lane == 0) lds_wc[ppar][w] = c2c | (cn2c << 16);
            RAW_BARRIER();
            const u64* cp = lds_wc[ppar];
            const u64 ct = cp[0] + cp[1] + cp[2] + cp[3];
            const u64 co = (w > 0 ? cp[0] : 0) + (w > 1 ? cp[1] : 0)
                         + (w > 2 ? cp[2] : 0);
            totalB  = (int)(ct & 0xFFFF);
            total2B = (int)((ct >> 16) & 0xFFFF);
            woff2   = (int)(co & 0xFFFF);
        } else {
#pragma unroll
            for (int k = 0; k < 4; ++k) { B2u[k] = B2p[k]; v2u[k] = v2pp[k]; }
            totalB  = (int)((tot >> 32) & 0xFFFF);
            total2B = (int)(tot >> 48);
            woff2   = (int)((off >> 32) & 0xFFFF);
        }

        const int T2 = (int)(__popcll(B2u[0] & lmask_lt) + __popcll(B2u[1] & lmask_lt)
                           + __popcll(B2u[2] & lmask_lt) + __popcll(B2u[3] & lmask_lt));
        int run2 = 0;
        v4f sv2;
#pragma unroll
        for (int k = 0; k < 4; ++k) {
            const bool bk = (B2u[k] >> lane) & 1ull;
            const int lt = woff2 + T2 + run2;
            run2 += bk;
            const int slot = bk ? lt : (totalB + (n0 + k) - lt);
            if (slot < SS)
                __builtin_nontemporal_store((float)(n0 + k),
                                            &out_ids2[row * SS + slot]);
            sv2[k] = bk ? 0.0f : v2u[k];
            v2[k] = sv2[k];
        }
        __builtin_nontemporal_store(sv2, (v4f*)(out_st2 + row * NN + n0));
        if (i == 0) {
            __builtin_nontemporal_store((float)totalB,  &out_cnt2[row * 2 + 0]);
            __builtin_nontemporal_store((float)total2B, &out_cnt2[row * 2 + 1]);
        }
    };

    v4f f0 = *(const v4f*)(I1buf + ((size_t)0 * BATCH + b) * NN + n0);
    v4f f1 = (nsteps > 1)
        ? *(const v4f*)(I1buf + ((size_t)1 * BATCH + b) * NN + n0) : f0;

    for (int tt = 0; tt < nsteps; ++tt) {
        const int par = tt & 1;
        v4f f2 = f0;
        if (tt + 2 < nsteps)
            f2 = *(const v4f*)(I1buf + ((size_t)(tt + 2) * BATCH + b) * NN + n0);

        if (tt > 0) CONSUME(t0 + tt - 1, par ^ 1);

        const v4f f = f0; f0 = f1; f1 = f2;
        u64 Bn1[4], Bn2[4];
#pragma unroll
        for (int k = 0; k < 4; ++k) {
            v1[k] = __fadd_rn(__fmul_rn(d1v[k], v1[k]), __fmul_rn(o1v[k], f[k]));
            B1p[k] = __ballot(v1[k] > t1v[k]);
            Bn1[k] = __ballot(v1[k] > t1bv[k]);
            if ((B1p[k] >> lane) & 1ull) v1[k] = 0.0f;
            v2pp[k] = __fmul_rn(d2v[k], v2[k]);
            B2p[k] = __ballot(v2pp[k] > t2v[k]);
            Bn2[k] = __ballot(v2pp[k] > t2bv[k]);
        }
        const u64 c1  = __popcll(B1p[0]) + __popcll(B1p[1])
                      + __popcll(B1p[2]) + __popcll(B1p[3]);
        const u64 cn1 = __popcll(Bn1[0]) + __popcll(Bn1[1])
                      + __popcll(Bn1[2]) + __popcll(Bn1[3]);
        const u64 c2  = __popcll(B2p[0]) + __popcll(B2p[1])
                      + __popcll(B2p[2]) + __popcll(B2p[3]);
        const u64 cn2 = __popcll(Bn2[0]) + __popcll(Bn2[1])
                      + __popcll(Bn2[2]) + __popcll(Bn2[3]);
        if (lane == 0)
            lds_w[par][w] = c1 | (cn1 << 16) | (c2 << 32) | (cn2 << 48);

        RAW_BARRIER();
    }

    CONSUME(t0 + nsteps - 1, (nsteps - 1) & 1);

#pragma unroll
    for (int k = 0; k < 4; ++k) {
        state_out[0 * BATCH * NN + b * NN + n0 + k] = v1[k];
        state_out[1 * BATCH * NN + b * NN + n0 + k] = v2[k];
    }
}

extern "C" void kernel_launch(void* const* d_in, const int* in_sizes, int n_in,
                              void* d_out, int out_size, void* d_ws, size_t ws_size,
                              hipStream_t stream) {
    const float* W1     = (const float*)d_in[0];
    const float* W2     = (const float*)d_in[1];
    const float* decay1 = (const float*)d_in[2];
    const float* decay2 = (const float*)d_in[3];
    const float* th1    = (const float*)d_in[4];
    const float* th2    = (const float*)d_in[5];
    const float* init1  = (const float*)d_in[6];
    const float* init2  = (const float*)d_in[7];
    const int* inp_ids  = (const int*)d_in[8];
    const int* inp_num  = (const int*)d_in[9];
    float* out = (float*)d_out;

    char* p = (char*)d_ws;
    float* W1T    = (float*)p;                         p += (size_t)NN * NN * 4;
    float* stateA = (float*)p;                         p += (size_t)2 * BATCH * NN * 4;
    float* stateB = (float*)p;                         p += (size_t)2 * BATCH * NN * 4;
    u64*   pc     = (u64*)p;                           p += (size_t)SEQ * BATCH * 4 * 8;
    unsigned* flags = (unsigned*)p;                    p += 256;
    float* I1buf  = (float*)p;
    const size_t used  = (size_t)(p - (char*)d_ws);
    const size_t avail = ws_size > used ? ws_size - used : 0;
    int tc = (int)(avail / ((size_t)BATCH * NN * 4));
    if (tc > SEQ) tc = SEQ;
    if (tc < 1) tc = 1;

    dim3 tb(32, 8, 1), tg(NN / 32, NN / 32, 1);
    transpose1<<<tg, tb, 0, stream>>>(W1, W1T);
    // identity ids for all (t,b) of both layers
    ids_fill<<<(2 * SEQ * BATCH * SS / 4) / 256, 256, 0, stream>>>(out);

    float* sin  = stateA;
    float* sout = stateB;
    for (int t0 = 0; t0 < SEQ; t0 += tc) {
        const int nst = (SEQ - t0 < tc) ? (SEQ - t0) : tc;
        hipMemsetAsync(flags, 0, BATCH * sizeof(unsigned), stream);
        gather_kernel<<<nst * BATCH, 256, 0, stream>>>(W1T, inp_ids, inp_num,
                                                       I1buf, t0);
        scan_kernel<<<4 * BATCH, 64, 0, stream>>>(I1buf, decay1, decay2, th1, th2,
                                                  init1, init2, sin, sout,
                                                  pc, flags, out, t0, nst);
        const int RB = (nst * BATCH + 255) / 256;
        finish_kernel<<<RB + BATCH, 256, 0, stream>>>(pc, I1buf, W2,
                                                      decay1, decay2, th1, th2,
                                                      init1, init2, sin, sout,
                                                      flags, out, t0, nst, RB);
        float* tmp = sin; sin = sout; sout = tmp;
    }
}

// Round 19
// 578.305 us; speedup vs baseline: 1.3009x; 1.0329x over previous
//
#include <hip/hip_runtime.h>

#define SEQ 512
#define BATCH 64
#define NN 1024
#define SS 64

typedef float v4f __attribute__((ext_vector_type(4)));
typedef unsigned long long u64;

// lgkm-only barrier (no vmcnt drain) — fallback path only
#define RAW_BARRIER() asm volatile("s_waitcnt lgkmcnt(0)\n\ts_barrier" ::: "memory")

// ---- transpose W1 (1024x1024 f32): W1T[i*N+j] = W1[j*N+i] ----
__global__ void transpose1(const float* __restrict__ A, float* __restrict__ At) {
    __shared__ float tile[32][33];
    int bx = blockIdx.x * 32, by = blockIdx.y * 32;
    int tx = threadIdx.x, ty = threadIdx.y;   // block 32x8
#pragma unroll
    for (int r = 0; r < 32; r += 8)
        tile[ty + r][tx] = A[(by + ty + r) * NN + (bx + tx)];
    __syncthreads();
#pragma unroll
    for (int r = 0; r < 32; r += 8)
        At[(bx + ty + r) * NN + (by + tx)] = tile[tx][ty + r];
}

// ---- identity ids pattern for ALL (t,b) rows of ids1|ids2 (exact when no
// spikes; fallback overwrites flagged batches later in stream order) ----
__global__ __launch_bounds__(256) void ids_fill(float* __restrict__ out_ids) {
    const int idx = blockIdx.x * 256 + threadIdx.x;       // one v4f per thread
    const int p4  = (idx & 15) << 2;                      // position in 64-row
    const v4f val = {(float)p4, (float)(p4 + 1), (float)(p4 + 2), (float)(p4 + 3)};
    __builtin_nontemporal_store(val, (v4f*)(out_ids + (size_t)idx * 4));
}

// ---- phase 1: I1[tt,b,n] = sum_{s<num} W1T[ids[s], n] (R15-proven config:
// cached store so scan reads hit L2/L3) ----
__global__ __launch_bounds__(256) void gather_kernel(
    const float* __restrict__ W1T,
    const int* __restrict__ inp_ids, const int* __restrict__ inp_num,
    float* __restrict__ I1buf, int t0)
{
    const int bid = blockIdx.x;
    const int tt  = bid >> 6;
    const int b   = bid & 63;
    const int t   = t0 + tt;
    const int j4  = threadIdx.x << 2;
    const int num = inp_num[t * BATCH + b];
    const int* ids = inp_ids + ((size_t)t * BATCH + b) * SS;  // uniform -> s_load

    v4f a0 = {0,0,0,0}, a1 = a0, a2 = a0, a3 = a0;
    const int nch = num >> 2;
    const int rem = num & 3;
#pragma unroll
    for (int c = 0; c < 16; ++c) {
        if (c < nch) {                             // block-uniform
            const int r = c << 2;
            const v4f w0 = *(const v4f*)(W1T + ((size_t)ids[r+0] << 10) + j4);
            const v4f w1 = *(const v4f*)(W1T + ((size_t)ids[r+1] << 10) + j4);
            const v4f w2 = *(const v4f*)(W1T + ((size_t)ids[r+2] << 10) + j4);
            const v4f w3 = *(const v4f*)(W1T + ((size_t)ids[r+3] << 10) + j4);
#pragma unroll
            for (int k = 0; k < 4; ++k) {
                a0[k] = __fadd_rn(a0[k], w0[k]);
                a1[k] = __fadd_rn(a1[k], w1[k]);
                a2[k] = __fadd_rn(a2[k], w2[k]);
                a3[k] = __fadd_rn(a3[k], w3[k]);
            }
        }
    }
    if (rem > 0) {
        const int r4 = nch << 2;
        const v4f w0 = *(const v4f*)(W1T + ((size_t)ids[r4+0] << 10) + j4);
#pragma unroll
        for (int k = 0; k < 4; ++k) a0[k] = __fadd_rn(a0[k], w0[k]);
        if (rem > 1) {
            const v4f w1 = *(const v4f*)(W1T + ((size_t)ids[r4+1] << 10) + j4);
#pragma unroll
            for (int k = 0; k < 4; ++k) a1[k] = __fadd_rn(a1[k], w1[k]);
        }
        if (rem > 2) {
            const v4f w2 = *(const v4f*)(W1T + ((size_t)ids[r4+2] << 10) + j4);
#pragma unroll
            for (int k = 0; k < 4; ++k) a2[k] = __fadd_rn(a2[k], w2[k]);
        }
    }
    v4f o;
#pragma unroll
    for (int k = 0; k < 4; ++k)
        o[k] = __fadd_rn(__fadd_rn(a0[k], a1[k]), __fadd_rn(a2[k], a3[k]));
    *(v4f*)(I1buf + ((size_t)tt * BATCH + b) * NN + j4) = o;   // cached store
}

// ---- phase 2a: lane-local scan with ZERO cross-lane ops in the loop.
// Speculation: no spikes AND no near-threshold events -> counts all zero
// (cnt region pre-zeroed), ids identity (ids_fill), resets no-ops.
// Guard (lane-local): near |= v1 > 0.9*t1 | v2 > 0.9*t2 — subsumes spikes
// (0.9*th < th for th>0) and nonzero counts. One ballot at END only.
__global__ __launch_bounds__(64) void scan_kernel(
    const float* __restrict__ I1buf,
    const float* __restrict__ decay1, const float* __restrict__ decay2,
    const float* __restrict__ th1, const float* __restrict__ th2,
    const float* __restrict__ init1, const float* __restrict__ init2,
    const float* __restrict__ state_in, float* __restrict__ state_out,
    unsigned* __restrict__ flags, float* __restrict__ out, int t0, int nst)
{
    const int bid = blockIdx.x;
    const int b   = bid >> 2;
    const int q   = bid & 3;
    const int tid = threadIdx.x;            // 0..63 (one wave)
    const int n0  = (q << 8) + (tid << 2);  // neurons n0..n0+3

    float v1[4], v2[4], d1v[4], d2v[4], o1v[4];
    float t1v[4], t2v[4], t1bv[4], t2bv[4];
    const float* v1src = t0 ? (state_in + 0 * BATCH * NN) : init1;
    const float* v2src = t0 ? (state_in + 1 * BATCH * NN) : init2;
#pragma unroll
    for (int k = 0; k < 4; ++k) {
        const int n = n0 + k;
        v1[k] = v1src[b * NN + n];  v2[k] = v2src[b * NN + n];
        d1v[k] = decay1[n];  d2v[k] = decay2[n];
        t1v[k] = th1[n];     t2v[k] = th2[n];
        t1bv[k] = __fmul_rn(0.9f, t1v[k]);
        t2bv[k] = __fmul_rn(0.9f, t2v[k]);
        o1v[k] = __fadd_rn(1.0f, -d1v[k]);
    }

    float* out_st1 = out + (size_t)2 * SEQ * BATCH * SS + (size_t)2 * SEQ * BATCH * 2;
    float* out_st2 = out_st1 + (size_t)SEQ * BATCH * NN;

    int near = 0;                           // lane-local guard accumulator

    // depth-8 I1 prefetch ring (static indices; tail-clamped loads harmless)
    v4f f[8];
#pragma unroll
    for (int j = 0; j < 8; ++j) {
        const int tt = (j < nst) ? j : (nst - 1);
        f[j] = *(const v4f*)(I1buf + ((size_t)tt * BATCH + b) * NN + n0);
    }

    for (int g = 0; g < nst; g += 8) {
#pragma unroll
        for (int j = 0; j < 8; ++j) {
            const int tt = g + j;
            if (tt < nst) {                 // uniform guard
                const v4f cur = f[j];
                const int tp = (tt + 8 < nst) ? (tt + 8) : (nst - 1);
                f[j] = *(const v4f*)(I1buf + ((size_t)tp * BATCH + b) * NN + n0);

#pragma unroll
                for (int k = 0; k < 4; ++k) {
                    v1[k] = __fadd_rn(__fmul_rn(d1v[k], v1[k]),
                                      __fmul_rn(o1v[k], cur[k]));
                    near |= (v1[k] > t1bv[k]);           // lane-local guard
                    if (v1[k] > t1v[k]) v1[k] = 0.0f;    // exact reset (lane-local)
                    v2[k] = __fmul_rn(d2v[k], v2[k]);    // I2=0 spec
                    near |= (v2[k] > t2bv[k]);
                    if (v2[k] > t2v[k]) v2[k] = 0.0f;
                }

                const size_t row = (size_t)(t0 + tt) * BATCH + b;
                const v4f s1 = {v1[0], v1[1], v1[2], v1[3]};
                const v4f s2 = {v2[0], v2[1], v2[2], v2[3]};
                __builtin_nontemporal_store(s1, (v4f*)(out_st1 + row * NN + n0));
                __builtin_nontemporal_store(s2, (v4f*)(out_st2 + row * NN + n0));
            }
        }
    }

    // single cross-lane op per scan (not per step)
    if (__ballot(near != 0)) {
        if (tid == 0) flags[b] = 1u;        // batch needs exact fallback
    }

#pragma unroll
    for (int k = 0; k < 4; ++k) {
        state_out[0 * BATCH * NN + b * NN + n0 + k] = v1[k];
        state_out[1 * BATCH * NN + b * NN + n0 + k] = v2[k];
    }
}

// ---- phase 2c: exact fallback (R13 lif body), only for flagged batches ----
__global__ __launch_bounds__(256, 1) void fallback_kernel(
    const float* __restrict__ I1buf, const float* __restrict__ W2,
    const float* __restrict__ decay1, const float* __restrict__ decay2,
    const float* __restrict__ th1, const float* __restrict__ th2,
    const float* __restrict__ init1, const float* __restrict__ init2,
    const float* __restrict__ state_in, float* __restrict__ state_out,
    const unsigned* __restrict__ flags, float* __restrict__ out,
    int t0, int nsteps)
{
    const int b = blockIdx.x;
    if (flags[b] == 0u) return;                    // common case: null work

    const int i    = threadIdx.x;
    const int lane = i & 63;
    const int w    = i >> 6;
    const int n0   = i << 2;

    __shared__ u64 lds_w[2][4];
    __shared__ u64 lds_wc[2][4];
    __shared__ int lds_slots[NN];

    float v1[4], v2[4], d1v[4], d2v[4], o1v[4], o2v[4];
    float t1v[4], t2v[4], t1bv[4], t2bv[4];
    const float* v1src = t0 ? (state_in + 0 * BATCH * NN) : init1;
    const float* v2src = t0 ? (state_in + 1 * BATCH * NN) : init2;
#pragma unroll
    for (int k = 0; k < 4; ++k) {
        const int n = n0 + k;
        v1[k] = v1src[b * NN + n];  v2[k] = v2src[b * NN + n];
        d1v[k] = decay1[n];  d2v[k] = decay2[n];
        t1v[k] = th1[n];     t2v[k] = th2[n];
        t1bv[k] = __fmul_rn(0.9f, t1v[k]);
        t2bv[k] = __fmul_rn(0.9f, t2v[k]);
        o1v[k] = __fadd_rn(1.0f, -d1v[k]);
        o2v[k] = __fadd_rn(1.0f, -d2v[k]);
    }

    float* out_ids1 = out;
    float* out_ids2 = out + (size_t)SEQ * BATCH * SS;
    float* out_cnt1 = out + (size_t)2 * SEQ * BATCH * SS;
    float* out_cnt2 = out_cnt1 + (size_t)SEQ * BATCH * 2;
    float* out_st1  = out_cnt2 + (size_t)SEQ * BATCH * 2;
    float* out_st2  = out_st1  + (size_t)SEQ * BATCH * NN;

    const u64 lmask_lt = (1ull << lane) - 1ull;

    u64 B1p[4], B2p[4];
    float v2pp[4];

    auto CONSUME = [&](int s, int ppar) {
        const u64* wp = lds_w[ppar];
        const u64 x0 = wp[0], x1 = wp[1], x2 = wp[2], x3 = wp[3];
        const u64 tot = x0 + x1 + x2 + x3;
        const u64 off = (w > 0 ? x0 : 0) + (w > 1 ? x1 : 0) + (w > 2 ? x2 : 0);
        const int totalA  = (int)(tot & 0xFFFF);
        const int total2A = (int)((tot >> 16) & 0xFFFF);
        const int woff1   = (int)(off & 0xFFFF);

        const int T1 = (int)(__popcll(B1p[0] & lmask_lt) + __popcll(B1p[1] & lmask_lt)
                           + __popcll(B1p[2] & lmask_lt) + __popcll(B1p[3] & lmask_lt));
        const size_t row = (size_t)s * BATCH + b;

        int run = 0;
        int lt1s[4]; bool bk1[4];
#pragma unroll
        for (int k = 0; k < 4; ++k) {
            bk1[k] = (B1p[k] >> lane) & 1ull;
            lt1s[k] = woff1 + T1 + run;
            run += bk1[k];
            const int slot = bk1[k] ? lt1s[k] : (totalA + (n0 + k) - lt1s[k]);
            if (slot < SS)
                __builtin_nontemporal_store((float)(n0 + k),
                                            &out_ids1[row * SS + slot]);
        }
        {
            const v4f sv = {v1[0], v1[1], v1[2], v1[3]};
            __builtin_nontemporal_store(sv, (v4f*)(out_st1 + row * NN + n0));
        }
        if (i == 0) {
            __builtin_nontemporal_store((float)totalA,  &out_cnt1[row * 2 + 0]);
            __builtin_nontemporal_store((float)total2A, &out_cnt1[row * 2 + 1]);
        }

        int totalB, total2B, woff2;
        u64 B2u[4]; float v2u[4];
        if (totalA > 0) {
#pragma unroll
            for (int k = 0; k < 4; ++k)
                if (bk1[k]) lds_slots[lt1s[k]] = n0 + k;
            RAW_BARRIER();
            float I2[4] = {0.0f, 0.0f, 0.0f, 0.0f};
            for (int kk = 0; kk < totalA; ++kk) {
                const int sid = lds_slots[kk];
#pragma unroll
                for (int k = 0; k < 4; ++k)
                    I2[k] = __fadd_rn(I2[k], W2[(size_t)(n0 + k) * NN + sid]);
            }
            u64 Bn2c[4];
#pragma unroll
            for (int k = 0; k < 4; ++k) {
                v2u[k] = __fadd_rn(v2pp[k], __fmul_rn(o2v[k], I2[k]));
                B2u[k] = __ballot(v2u[k] > t2v[k]);
                Bn2c[k] = __ballot(v2u[k] > t2bv[k]);
            }
            const u64 c2c  = __popcll(B2u[0]) + __popcll(B2u[1])
                           + __popcll(B2u[2]) + __popcll(B2u[3]);
            const u64 cn2c = __popcll(Bn2c[0]) + __popcll(Bn2c[1])
                           + __popcll(Bn2c[2]) + __popcll(Bn2c[3]);
            if (lane == 0) lds_wc[ppar][w] = c2c | (cn2c << 16);
            RAW_BARRIER();
            const u64* cp = lds_wc[ppar];
            const u64 ct = cp[0] + cp[1] + cp[2] + cp[3];
            const u64 co = (w > 0 ? cp[0] : 0) + (w > 1 ? cp[1] : 0)
                         + (w > 2 ? cp[2] : 0);
            totalB  = (int)(ct & 0xFFFF);
            total2B = (int)((ct >> 16) & 0xFFFF);
            woff2   = (int)(co & 0xFFFF);
        } else {
#pragma unroll
            for (int k = 0; k < 4; ++k) { B2u[k] = B2p[k]; v2u[k] = v2pp[k]; }
            totalB  = (int)((tot >> 32) & 0xFFFF);
            total2B = (int)(tot >> 48);
            woff2   = (int)((off >> 32) & 0xFFFF);
        }

        const int T2 = (int)(__popcll(B2u[0] & lmask_lt) + __popcll(B2u[1] & lmask_lt)
                           + __popcll(B2u[2] & lmask_lt) + __popcll(B2u[3] & lmask_lt));
        int run2 = 0;
        v4f sv2;
#pragma unroll
        for (int k = 0; k < 4; ++k) {
            const bool bk = (B2u[k] >> lane) & 1ull;
            const int lt = woff2 + T2 + run2;
            run2 += bk;
            const int slot = bk ? lt : (totalB + (n0 + k) - lt);
            if (slot < SS)
                __builtin_nontemporal_store((float)(n0 + k),
                                            &out_ids2[row * SS + slot]);
            sv2[k] = bk ? 0.0f : v2u[k];
            v2[k] = sv2[k];
        }
        __builtin_nontemporal_store(sv2, (v4f*)(out_st2 + row * NN + n0));
        if (i == 0) {
            __builtin_nontemporal_store((float)totalB,  &out_cnt2[row * 2 + 0]);
            __builtin_nontemporal_store((float)total2B, &out_cnt2[row * 2 + 1]);
        }
    };

    v4f f0 = *(const v4f*)(I1buf + ((size_t)0 * BATCH + b) * NN + n0);
    v4f f1 = (nsteps > 1)
        ? *(const v4f*)(I1buf + ((size_t)1 * BATCH + b) * NN + n0) : f0;

    for (int tt = 0; tt < nsteps; ++tt) {
        const int par = tt & 1;
        v4f f2 = f0;
        if (tt + 2 < nsteps)
            f2 = *(const v4f*)(I1buf + ((size_t)(tt + 2) * BATCH + b) * NN + n0);

        if (tt > 0) CONSUME(t0 + tt - 1, par ^ 1);

        const v4f f = f0; f0 = f1; f1 = f2;
        u64 Bn1[4], Bn2[4];
#pragma unroll
        for (int k = 0; k < 4; ++k) {
            v1[k] = __fadd_rn(__fmul_rn(d1v[k], v1[k]), __fmul_rn(o1v[k], f[k]));
            B1p[k] = __ballot(v1[k] > t1v[k]);
            Bn1[k] = __ballot(v1[k] > t1bv[k]);
            if ((B1p[k] >> lane) & 1ull) v1[k] = 0.0f;
            v2pp[k] = __fmul_rn(d2v[k], v2[k]);
            B2p[k] = __ballot(v2pp[k] > t2v[k]);
            Bn2[k] = __ballot(v2pp[k] > t2bv[k]);
        }
        const u64 c1  = __popcll(B1p[0]) + __popcll(B1p[1])
                      + __popcll(B1p[2]) + __popcll(B1p[3]);
        const u64 cn1 = __popcll(Bn1[0]) + __popcll(Bn1[1])
                      + __popcll(Bn1[2]) + __popcll(Bn1[3]);
        const u64 c2  = __popcll(B2p[0]) + __popcll(B2p[1])
                      + __popcll(B2p[2]) + __popcll(B2p[3]);
        const u64 cn2 = __popcll(Bn2[0]) + __popcll(Bn2[1])
                      + __popcll(Bn2[2]) + __popcll(Bn2[3]);
        if (lane == 0)
            lds_w[par][w] = c1 | (cn1 << 16) | (c2 << 32) | (cn2 << 48);

        RAW_BARRIER();
    }

    CONSUME(t0 + nsteps - 1, (nsteps - 1) & 1);

#pragma unroll
    for (int k = 0; k < 4; ++k) {
        state_out[0 * BATCH * NN + b * NN + n0 + k] = v1[k];
        state_out[1 * BATCH * NN + b * NN + n0 + k] = v2[k];
    }
}

extern "C" void kernel_launch(void* const* d_in, const int* in_sizes, int n_in,
                              void* d_out, int out_size, void* d_ws, size_t ws_size,
                              hipStream_t stream) {
    const float* W1     = (const float*)d_in[0];
    const float* W2     = (const float*)d_in[1];
    const float* decay1 = (const float*)d_in[2];
    const float* decay2 = (const float*)d_in[3];
    const float* th1    = (const float*)d_in[4];
    const float* th2    = (const float*)d_in[5];
    const float* init1  = (const float*)d_in[6];
    const float* init2  = (const float*)d_in[7];
    const int* inp_ids  = (const int*)d_in[8];
    const int* inp_num  = (const int*)d_in[9];
    float* out = (float*)d_out;

    char* p = (char*)d_ws;
    float* W1T    = (float*)p;                         p += (size_t)NN * NN * 4;
    float* stateA = (float*)p;                         p += (size_t)2 * BATCH * NN * 4;
    float* stateB = (float*)p;                         p += (size_t)2 * BATCH * NN * 4;
    unsigned* flags = (unsigned*)p;                    p += 256;
    float* I1buf  = (float*)p;
    const size_t used  = (size_t)(p - (char*)d_ws);
    const size_t avail = ws_size > used ? ws_size - used : 0;
    int tc = (int)(avail / ((size_t)BATCH * NN * 4));
    if (tc > SEQ) tc = SEQ;
    if (tc < 1) tc = 1;

    float* out_cnt = out + (size_t)2 * SEQ * BATCH * SS;

    dim3 tb(32, 8, 1), tg(NN / 32, NN / 32, 1);
    transpose1<<<tg, tb, 0, stream>>>(W1, W1T);
    // identity ids for all (t,b) of both layers; zero cnt region (spec: all zero)
    ids_fill<<<(2 * SEQ * BATCH * SS / 4) / 256, 256, 0, stream>>>(out);
    hipMemsetAsync(out_cnt, 0, (size_t)2 * SEQ * BATCH * 2 * 4, stream);

    float* sin  = stateA;
    float* sout = stateB;
    for (int t0 = 0; t0 < SEQ; t0 += tc) {
        const int nst = (SEQ - t0 < tc) ? (SEQ - t0) : tc;
        hipMemsetAsync(flags, 0, BATCH * sizeof(unsigned), stream);
        gather_kernel<<<nst * BATCH, 256, 0, stream>>>(W1T, inp_ids, inp_num,
                                                       I1buf, t0);
        scan_kernel<<<4 * BATCH, 64, 0, stream>>>(I1buf, decay1, decay2, th1, th2,
                                                  init1, init2, sin, sout,
                                                  flags, out, t0, nst);
        fallback_kernel<<<BATCH, 256, 0, stream>>>(I1buf, W2, decay1, decay2,
                                                   th1, th2, init1, init2,
                                                   sin, sout, flags, out, t0, nst);
        float* tmp = sin; sin = sout; sout = tmp;
    }
}

// Round 20
// 569.888 us; speedup vs baseline: 1.3201x; 1.0148x over previous
//
#include <hip/hip_runtime.h>

#define SEQ 512
#define BATCH 64
#define NN 1024
#define SS 64

typedef float v4f __attribute__((ext_vector_type(4)));
typedef unsigned long long u64;

// lgkm-only barrier (no vmcnt drain) — fallback path only
#define RAW_BARRIER() asm volatile("s_waitcnt lgkmcnt(0)\n\ts_barrier" ::: "memory")

// ---- transpose W1 (1024x1024 f32): W1T[i*N+j] = W1[j*N+i] ----
__global__ void transpose1(const float* __restrict__ A, float* __restrict__ At) {
    __shared__ float tile[32][33];
    int bx = blockIdx.x * 32, by = blockIdx.y * 32;
    int tx = threadIdx.x, ty = threadIdx.y;   // block 32x8
#pragma unroll
    for (int r = 0; r < 32; r += 8)
        tile[ty + r][tx] = A[(by + ty + r) * NN + (bx + tx)];
    __syncthreads();
#pragma unroll
    for (int r = 0; r < 32; r += 8)
        At[(bx + ty + r) * NN + (by + tx)] = tile[tx][ty + r];
}

// ---- prologue fill: identity ids for ids1|ids2, zero cnt region, zero flags.
// (exact when no spikes; fallback overwrites flagged batches later in stream)
__global__ __launch_bounds__(256) void fill_outputs(float* __restrict__ out,
                                                    unsigned* __restrict__ flags) {
    const int idx = blockIdx.x * 256 + threadIdx.x;       // one v4f per thread
    const int p4  = (idx & 15) << 2;                      // position in 64-row
    const v4f val = {(float)p4, (float)(p4 + 1), (float)(p4 + 2), (float)(p4 + 3)};
    __builtin_nontemporal_store(val, (v4f*)(out + (size_t)idx * 4));
    // cnt region: 2*SEQ*BATCH*2 floats = 32768 v4f, zero-filled
    if (idx < 2 * SEQ * BATCH * 2 / 4) {
        const v4f z = {0.0f, 0.0f, 0.0f, 0.0f};
        __builtin_nontemporal_store(z,
            (v4f*)(out + (size_t)2 * SEQ * BATCH * SS + (size_t)idx * 4));
    }
    if (idx < 16) ((v4f*)flags)[idx] = (v4f){0.0f, 0.0f, 0.0f, 0.0f};
}

// ---- phase 1: I1[tt,b,n] = sum_{s<num} W1T[ids[s], n] (R15-proven config:
// cached store so scan reads hit L2/L3) ----
__global__ __launch_bounds__(256) void gather_kernel(
    const float* __restrict__ W1T,
    const int* __restrict__ inp_ids, const int* __restrict__ inp_num,
    float* __restrict__ I1buf, int t0)
{
    const int bid = blockIdx.x;
    const int tt  = bid >> 6;
    const int b   = bid & 63;
    const int t   = t0 + tt;
    const int j4  = threadIdx.x << 2;
    const int num = inp_num[t * BATCH + b];
    const int* ids = inp_ids + ((size_t)t * BATCH + b) * SS;  // uniform -> s_load

    v4f a0 = {0,0,0,0}, a1 = a0, a2 = a0, a3 = a0;
    const int nch = num >> 2;
    const int rem = num & 3;
#pragma unroll
    for (int c = 0; c < 16; ++c) {
        if (c < nch) {                             // block-uniform
            const int r = c << 2;
            const v4f w0 = *(const v4f*)(W1T + ((size_t)ids[r+0] << 10) + j4);
            const v4f w1 = *(const v4f*)(W1T + ((size_t)ids[r+1] << 10) + j4);
            const v4f w2 = *(const v4f*)(W1T + ((size_t)ids[r+2] << 10) + j4);
            const v4f w3 = *(const v4f*)(W1T + ((size_t)ids[r+3] << 10) + j4);
#pragma unroll
            for (int k = 0; k < 4; ++k) {
                a0[k] = __fadd_rn(a0[k], w0[k]);
                a1[k] = __fadd_rn(a1[k], w1[k]);
                a2[k] = __fadd_rn(a2[k], w2[k]);
                a3[k] = __fadd_rn(a3[k], w3[k]);
            }
        }
    }
    if (rem > 0) {
        const int r4 = nch << 2;
        const v4f w0 = *(const v4f*)(W1T + ((size_t)ids[r4+0] << 10) + j4);
#pragma unroll
        for (int k = 0; k < 4; ++k) a0[k] = __fadd_rn(a0[k], w0[k]);
        if (rem > 1) {
            const v4f w1 = *(const v4f*)(W1T + ((size_t)ids[r4+1] << 10) + j4);
#pragma unroll
            for (int k = 0; k < 4; ++k) a1[k] = __fadd_rn(a1[k], w1[k]);
        }
        if (rem > 2) {
            const v4f w2 = *(const v4f*)(W1T + ((size_t)ids[r4+2] << 10) + j4);
#pragma unroll
            for (int k = 0; k < 4; ++k) a2[k] = __fadd_rn(a2[k], w2[k]);
        }
    }
    v4f o;
#pragma unroll
    for (int k = 0; k < 4; ++k)
        o[k] = __fadd_rn(__fadd_rn(a0[k], a1[k]), __fadd_rn(a2[k], a3[k]));
    *(v4f*)(I1buf + ((size_t)tt * BATCH + b) * NN + j4) = o;   // cached store
}

// ---- phase 2a: lane-local scan, zero cross-lane ops in the loop.
// Single change vs R19: I1 prefetch ring depth 8 -> 16 (L3-latency theory).
__global__ __launch_bounds__(64) void scan_kernel(
    const float* __restrict__ I1buf,
    const float* __restrict__ decay1, const float* __restrict__ decay2,
    const float* __restrict__ th1, const float* __restrict__ th2,
    const float* __restrict__ init1, const float* __restrict__ init2,
    const float* __restrict__ state_in, float* __restrict__ state_out,
    unsigned* __restrict__ flags, float* __restrict__ out, int t0, int nst)
{
    const int bid = blockIdx.x;
    const int b   = bid >> 2;
    const int q   = bid & 3;
    const int tid = threadIdx.x;            // 0..63 (one wave)
    const int n0  = (q << 8) + (tid << 2);  // neurons n0..n0+3

    float v1[4], v2[4], d1v[4], d2v[4], o1v[4];
    float t1v[4], t2v[4], t1bv[4], t2bv[4];
    const float* v1src = t0 ? (state_in + 0 * BATCH * NN) : init1;
    const float* v2src = t0 ? (state_in + 1 * BATCH * NN) : init2;
#pragma unroll
    for (int k = 0; k < 4; ++k) {
        const int n = n0 + k;
        v1[k] = v1src[b * NN + n];  v2[k] = v2src[b * NN + n];
        d1v[k] = decay1[n];  d2v[k] = decay2[n];
        t1v[k] = th1[n];     t2v[k] = th2[n];
        t1bv[k] = __fmul_rn(0.9f, t1v[k]);
        t2bv[k] = __fmul_rn(0.9f, t2v[k]);
        o1v[k] = __fadd_rn(1.0f, -d1v[k]);
    }

    float* out_st1 = out + (size_t)2 * SEQ * BATCH * SS + (size_t)2 * SEQ * BATCH * 2;
    float* out_st2 = out_st1 + (size_t)SEQ * BATCH * NN;

    int near = 0;                           // lane-local guard accumulator

    // depth-16 I1 prefetch ring (static indices; tail-clamped loads harmless)
    v4f f[16];
#pragma unroll
    for (int j = 0; j < 16; ++j) {
        const int tt = (j < nst) ? j : (nst - 1);
        f[j] = *(const v4f*)(I1buf + ((size_t)tt * BATCH + b) * NN + n0);
    }

    for (int g = 0; g < nst; g += 16) {
#pragma unroll
        for (int j = 0; j < 16; ++j) {
            const int tt = g + j;
            if (tt < nst) {                 // uniform guard
                const v4f cur = f[j];
                const int tp = (tt + 16 < nst) ? (tt + 16) : (nst - 1);
                f[j] = *(const v4f*)(I1buf + ((size_t)tp * BATCH + b) * NN + n0);

#pragma unroll
                for (int k = 0; k < 4; ++k) {
                    v1[k] = __fadd_rn(__fmul_rn(d1v[k], v1[k]),
                                      __fmul_rn(o1v[k], cur[k]));
                    near |= (v1[k] > t1bv[k]);           // lane-local guard
                    if (v1[k] > t1v[k]) v1[k] = 0.0f;    // exact reset (lane-local)
                    v2[k] = __fmul_rn(d2v[k], v2[k]);    // I2=0 spec
                    near |= (v2[k] > t2bv[k]);
                    if (v2[k] > t2v[k]) v2[k] = 0.0f;
                }

                const size_t row = (size_t)(t0 + tt) * BATCH + b;
                const v4f s1 = {v1[0], v1[1], v1[2], v1[3]};
                const v4f s2 = {v2[0], v2[1], v2[2], v2[3]};
                __builtin_nontemporal_store(s1, (v4f*)(out_st1 + row * NN + n0));
                __builtin_nontemporal_store(s2, (v4f*)(out_st2 + row * NN + n0));
            }
        }
    }

    // single cross-lane op per scan (not per step)
    if (__ballot(near != 0)) {
        if (tid == 0) flags[b] = 1u;        // batch needs exact fallback
    }

#pragma unroll
    for (int k = 0; k < 4; ++k) {
        state_out[0 * BATCH * NN + b * NN + n0 + k] = v1[k];
        state_out[1 * BATCH * NN + b * NN + n0 + k] = v2[k];
    }
}

// ---- phase 2c: exact fallback (R13 lif body), only for flagged batches ----
__global__ __launch_bounds__(256, 1) void fallback_kernel(
    const float* __restrict__ I1buf, const float* __restrict__ W2,
    const float* __restrict__ decay1, const float* __restrict__ decay2,
    const float* __restrict__ th1, const float* __restrict__ th2,
    const float* __restrict__ init1, const float* __restrict__ init2,
    const float* __restrict__ state_in, float* __restrict__ state_out,
    const unsigned* __restrict__ flags, float* __restrict__ out,
    int t0, int nsteps)
{
    const int b = blockIdx.x;
    if (flags[b] == 0u) return;                    // common case: null work

    const int i    = threadIdx.x;
    const int lane = i & 63;
    const int w    = i >> 6;
    const int n0   = i << 2;

    __shared__ u64 lds_w[2][4];
    __shared__ u64 lds_wc[2][4];
    __shared__ int lds_slots[NN];

    float v1[4], v2[4], d1v[4], d2v[4], o1v[4], o2v[4];
    float t1v[4], t2v[4], t1bv[4], t2bv[4];
    const float* v1src = t0 ? (state_in + 0 * BATCH * NN) : init1;
    const float* v2src = t0 ? (state_in + 1 * BATCH * NN) : init2;
#pragma unroll
    for (int k = 0; k < 4; ++k) {
        const int n = n0 + k;
        v1[k] = v1src[b * NN + n];  v2[k] = v2src[b * NN + n];
        d1v[k] = decay1[n];  d2v[k] = decay2[n];
        t1v[k] = th1[n];     t2v[k] = th2[n];
        t1bv[k] = __fmul_rn(0.9f, t1v[k]);
        t2bv[k] = __fmul_rn(0.9f, t2v[k]);
        o1v[k] = __fadd_rn(1.0f, -d1v[k]);
        o2v[k] = __fadd_rn(1.0f, -d2v[k]);
    }

    float* out_ids1 = out;
    float* out_ids2 = out + (size_t)SEQ * BATCH * SS;
    float* out_cnt1 = out + (size_t)2 * SEQ * BATCH * SS;
    float* out_cnt2 = out_cnt1 + (size_t)SEQ * BATCH * 2;
    float* out_st1  = out_cnt2 + (size_t)SEQ * BATCH * 2;
    float* out_st2  = out_st1  + (size_t)SEQ * BATCH * NN;

    const u64 lmask_lt = (1ull << lane) - 1ull;

    u64 B1p[4], B2p[4];
    float v2pp[4];

    auto CONSUME = [&](int s, int ppar) {
        const u64* wp = lds_w[ppar];
        const u64 x0 = wp[0], x1 = wp[1], x2 = wp[2], x3 = wp[3];
        const u64 tot = x0 + x1 + x2 + x3;
        const u64 off = (w > 0 ? x0 : 0) + (w > 1 ? x1 : 0) + (w > 2 ? x2 : 0);
        const int totalA  = (int)(tot & 0xFFFF);
        const int total2A = (int)((tot >> 16) & 0xFFFF);
        const int woff1   = (int)(off & 0xFFFF);

        const int T1 = (int)(__popcll(B1p[0] & lmask_lt) + __popcll(B1p[1] & lmask_lt)
                           + __popcll(B1p[2] & lmask_lt) + __popcll(B1p[3] & lmask_lt));
        const size_t row = (size_t)s * BATCH + b;

        int run = 0;
        int lt1s[4]; bool bk1[4];
#pragma unroll
        for (int k = 0; k < 4; ++k) {
            bk1[k] = (B1p[k] >> lane) & 1ull;
            lt1s[k] = woff1 + T1 + run;
            run += bk1[k];
            const int slot = bk1[k] ? lt1s[k] : (totalA + (n0 + k) - lt1s[k]);
            if (slot < SS)
                __builtin_nontemporal_store((float)(n0 + k),
                                            &out_ids1[row * SS + slot]);
        }
        {
            const v4f sv = {v1[0], v1[1], v1[2], v1[3]};
            __builtin_nontemporal_store(sv, (v4f*)(out_st1 + row * NN + n0));
        }
        if (i == 0) {
            __builtin_nontemporal_store((float)totalA,  &out_cnt1[row * 2 + 0]);
            __builtin_nontemporal_store((float)total2A, &out_cnt1[row * 2 + 1]);
        }

        int totalB, total2B, woff2;
        u64 B2u[4]; float v2u[4];
        if (totalA > 0) {
#pragma unroll
            for (int k = 0; k < 4; ++k)
                if (bk1[k]) lds_slots[lt1s[k]] = n0 + k;
            RAW_BARRIER();
            float I2[4] = {0.0f, 0.0f, 0.0f, 0.0f};
            for (int kk = 0; kk < totalA; ++kk) {
                const int sid = lds_slots[kk];
#pragma unroll
                for (int k = 0; k < 4; ++k)
                    I2[k] = __fadd_rn(I2[k], W2[(size_t)(n0 + k) * NN + sid]);
            }
            u64 Bn2c[4];
#pragma unroll
            for (int k = 0; k < 4; ++k) {
                v2u[k] = __fadd_rn(v2pp[k], __fmul_rn(o2v[k], I2[k]));
                B2u[k] = __ballot(v2u[k] > t2v[k]);
                Bn2c[k] = __ballot(v2u[k] > t2bv[k]);
            }
            const u64 c2c  = __popcll(B2u[0]) + __popcll(B2u[1])
                           + __popcll(B2u[2]) + __popcll(B2u[3]);
            const u64 cn2c = __popcll(Bn2c[0]) + __popcll(Bn2c[1])
                           + __popcll(Bn2c[2]) + __popcll(Bn2c[3]);
            if (lane == 0) lds_wc[ppar][w] = c2c | (cn2c << 16);
            RAW_BARRIER();
            const u64* cp = lds_wc[ppar];
            const u64 ct = cp[0] + cp[1] + cp[2] + cp[3];
            const u64 co = (w > 0 ? cp[0] : 0) + (w > 1 ? cp[1] : 0)
                         + (w > 2 ? cp[2] : 0);
            totalB  = (int)(ct & 0xFFFF);
            total2B = (int)((ct >> 16) & 0xFFFF);
            woff2   = (int)(co & 0xFFFF);
        } else {
#pragma unroll
            for (int k = 0; k < 4; ++k) { B2u[k] = B2p[k]; v2u[k] = v2pp[k]; }
            totalB  = (int)((tot >> 32) & 0xFFFF);
            total2B = (int)(tot >> 48);
            woff2   = (int)((off >> 32) & 0xFFFF);
        }

        const int T2 = (int)(__popcll(B2u[0] & lmask_lt) + __popcll(B2u[1] & lmask_lt)
                           + __popcll(B2u[2] & lmask_lt) + __popcll(B2u[3] & lmask_lt));
        int run2 = 0;
        v4f sv2;
#pragma unroll
        for (int k = 0; k < 4; ++k) {
            const bool bk = (B2u[k] >> lane) & 1ull;
            const int lt = woff2 + T2 + run2;
            run2 += bk;
            const int slot = bk ? lt : (totalB + (n0 + k) - lt);
            if (slot < SS)
                __builtin_nontemporal_store((float)(n0 + k),
                                            &out_ids2[row * SS + slot]);
            sv2[k] = bk ? 0.0f : v2u[k];
            v2[k] = sv2[k];
        }
        __builtin_nontemporal_store(sv2, (v4f*)(out_st2 + row * NN + n0));
        if (i == 0) {
            __builtin_nontemporal_store((float)totalB,  &out_cnt2[row * 2 + 0]);
            __builtin_nontemporal_store((float)total2B, &out_cnt2[row * 2 + 1]);
        }
    };

    v4f f0 = *(const v4f*)(I1buf + ((size_t)0 * BATCH + b) * NN + n0);
    v4f f1 = (nsteps > 1)
        ? *(const v4f*)(I1buf + ((size_t)1 * BATCH + b) * NN + n0) : f0;

    for (int tt = 0; tt < nsteps; ++tt) {
        const int par = tt & 1;
        v4f f2 = f0;
        if (tt + 2 < nsteps)
            f2 = *(const v4f*)(I1buf + ((size_t)(tt + 2) * BATCH + b) * NN + n0);

        if (tt > 0) CONSUME(t0 + tt - 1, par ^ 1);

        const v4f f = f0; f0 = f1; f1 = f2;
        u64 Bn1[4], Bn2[4];
#pragma unroll
        for (int k = 0; k < 4; ++k) {
            v1[k] = __fadd_rn(__fmul_rn(d1v[k], v1[k]), __fmul_rn(o1v[k], f[k]));
            B1p[k] = __ballot(v1[k] > t1v[k]);
            Bn1[k] = __ballot(v1[k] > t1bv[k]);
            if ((B1p[k] >> lane) & 1ull) v1[k] = 0.0f;
            v2pp[k] = __fmul_rn(d2v[k], v2[k]);
            B2p[k] = __ballot(v2pp[k] > t2v[k]);
            Bn2[k] = __ballot(v2pp[k] > t2bv[k]);
        }
        const u64 c1  = __popcll(B1p[0]) + __popcll(B1p[1])
                      + __popcll(B1p[2]) + __popcll(B1p[3]);
        const u64 cn1 = __popcll(Bn1[0]) + __popcll(Bn1[1])
                      + __popcll(Bn1[2]) + __popcll(Bn1[3]);
        const u64 c2  = __popcll(B2p[0]) + __popcll(B2p[1])
                      + __popcll(B2p[2]) + __popcll(B2p[3]);
        const u64 cn2 = __popcll(Bn2[0]) + __popcll(Bn2[1])
                      + __popcll(Bn2[2]) + __popcll(Bn2[3]);
        if (lane == 0)
            lds_w[par][w] = c1 | (cn1 << 16) | (c2 << 32) | (cn2 << 48);

        RAW_BARRIER();
    }

    CONSUME(t0 + nsteps - 1, (nsteps - 1) & 1);

#pragma unroll
    for (int k = 0; k < 4; ++k) {
        state_out[0 * BATCH * NN + b * NN + n0 + k] = v1[k];
        state_out[1 * BATCH * NN + b * NN + n0 + k] = v2[k];
    }
}

extern "C" void kernel_launch(void* const* d_in, const int* in_sizes, int n_in,
                              void* d_out, int out_size, void* d_ws, size_t ws_size,
                              hipStream_t stream) {
    const float* W1     = (const float*)d_in[0];
    const float* W2     = (const float*)d_in[1];
    const float* decay1 = (const float*)d_in[2];
    const float* decay2 = (const float*)d_in[3];
    const float* th1    = (const float*)d_in[4];
    const float* th2    = (const float*)d_in[5];
    const float* init1  = (const float*)d_in[6];
    const float* init2  = (const float*)d_in[7];
    const int* inp_ids  = (const int*)d_in[8];
    const int* inp_num  = (const int*)d_in[9];
    float* out = (float*)d_out;

    char* p = (char*)d_ws;
    float* W1T    = (float*)p;                         p += (size_t)NN * NN * 4;
    float* stateA = (float*)p;                         p += (size_t)2 * BATCH * NN * 4;
    float* stateB = (float*)p;                         p += (size_t)2 * BATCH * NN * 4;
    unsigned* flags = (unsigned*)p;                    p += 256;
    float* I1buf  = (float*)p;
    const size_t used  = (size_t)(p - (char*)d_ws);
    const size_t avail = ws_size > used ? ws_size - used : 0;
    int tc = (int)(avail / ((size_t)BATCH * NN * 4));
    if (tc > SEQ) tc = SEQ;
    if (tc < 1) tc = 1;

    dim3 tb(32, 8, 1), tg(NN / 32, NN / 32, 1);
    transpose1<<<tg, tb, 0, stream>>>(W1, W1T);
    // identity ids + zero cnt + zero flags, one prologue kernel
    fill_outputs<<<(2 * SEQ * BATCH * SS / 4) / 256, 256, 0, stream>>>(out, flags);

    float* sin  = stateA;
    float* sout = stateB;
    for (int t0 = 0; t0 < SEQ; t0 += tc) {
        const int nst = (SEQ - t0 < tc) ? (SEQ - t0) : tc;
        if (t0 > 0)   // first chunk's flags zeroed by fill_outputs
            hipMemsetAsync(flags, 0, BATCH * sizeof(unsigned), stream);
        gather_kernel<<<nst * BATCH, 256, 0, stream>>>(W1T, inp_ids, inp_num,
                                                       I1buf, t0);
        scan_kernel<<<4 * BATCH, 64, 0, stream>>>(I1buf, decay1, decay2, th1, th2,
                                                  init1, init2, sin, sout,
                                                  flags, out, t0, nst);
        fallback_kernel<<<BATCH, 256, 0, stream>>>(I1buf, W2, decay1, decay2,
                                                   th1, th2, init1, init2,
                                                   sin, sout, flags, out, t0, nst);
        float* tmp = sin; sin = sout; sout = tmp;
    }
}